// Round 14
// baseline (173.305 us; speedup 1.0000x reference)
//
#include <hip/hip_runtime.h>
#include <hip/hip_fp16.h>

#define N_NODES 50000
#define N_EDGES 600000
#define CAP 64   // bucket capacity per node (max degree ~40 for Poisson(12))

typedef _Float16 f16;
typedef f16 f16x8 __attribute__((ext_vector_type(8)));
typedef float f32x4 __attribute__((ext_vector_type(4)));
typedef unsigned int u32;
typedef unsigned long long u64;
typedef u32 u32x2 __attribute__((ext_vector_type(2)));
typedef u32 u32x4 __attribute__((ext_vector_type(4)));

#define WSCALE 33554432.0f   // 2^25

// ---------------- prep: dc init + f16 weights + permuted layer-1 bias ----------
// Feature-slot permutation (used by ALL feature buffers [N][64] u32):
//   slot s holds channels ch0 = (s>>4)*32 + (s&15)  (low16) and ch1 = ch0+16 (high16)
// This is exactly the MFMA D-fragment ownership (wave, m), so GEMM stores direct.

__global__ __launch_bounds__(256) void prep(const float* __restrict__ W1,
                                            const float* __restrict__ Wmu,
                                            const float* __restrict__ Wls,
                                            const float* __restrict__ b1,
                                            f16* __restrict__ Wc1,
                                            f16* __restrict__ Wc2,
                                            float2* __restrict__ b1p,
                                            u64* __restrict__ dc, int n) {
    int i = blockIdx.x * 256 + threadIdx.x;
    if (i < 16384) {
        Wc1[i] = (f16)W1[i];
        Wc2[i] = (f16)((i < 8192) ? Wmu[i] : Wls[i - 8192]);
    }
    if (i < 64) {
        int c0 = (i >> 4) * 32 + (i & 15);
        b1p[i] = make_float2(b1[c0], b1[c0 + 16]);
    }
    if (i < n) dc[i] = 0ULL;
}

// ---------------- bucket-CSR build: 8 edges/thread, one returning atomic each ----

#define HF_ATOMIC(i, rr, cc, ww) \
    bool k##i = (rr) != (cc); u64 old##i = 0; \
    if (k##i) old##i = atomicAdd(&dc[cc], (1ULL << 32) | (u64)(u32)__float2uint_rn((ww) * WSCALE));
#define HF_STORE(i, rr, cc, ww) \
    if (k##i) { u32x2 rec; rec.x = __float_as_uint(ww); rec.y = (u32)(rr); \
                sed[(cc) * CAP + (u32)(old##i >> 32)] = rec; }

__global__ __launch_bounds__(256) void hist_fill8(const int* __restrict__ ei,
                                                  const float* __restrict__ ew,
                                                  u64* __restrict__ dc,
                                                  u32x2* __restrict__ sed, int E) {
    int t = blockIdx.x * blockDim.x + threadIdx.x;
    if (8 * t >= E) return;                    // E % 8 == 0 -> all 8 valid
    const int4*   R4 = (const int4*)ei;
    const int4*   C4 = (const int4*)(ei + E);
    const float4* W4 = (const float4*)ew;
    int4 r0 = R4[2 * t], r1 = R4[2 * t + 1];
    int4 c0 = C4[2 * t], c1 = C4[2 * t + 1];
    float4 w0 = W4[2 * t], w1 = W4[2 * t + 1];

    HF_ATOMIC(0, r0.x, c0.x, w0.x) HF_ATOMIC(1, r0.y, c0.y, w0.y)
    HF_ATOMIC(2, r0.z, c0.z, w0.z) HF_ATOMIC(3, r0.w, c0.w, w0.w)
    HF_ATOMIC(4, r1.x, c1.x, w1.x) HF_ATOMIC(5, r1.y, c1.y, w1.y)
    HF_ATOMIC(6, r1.z, c1.z, w1.z) HF_ATOMIC(7, r1.w, c1.w, w1.w)

    HF_STORE(0, r0.x, c0.x, w0.x) HF_STORE(1, r0.y, c0.y, w0.y)
    HF_STORE(2, r0.z, c0.z, w0.z) HF_STORE(3, r0.w, c0.w, w0.w)
    HF_STORE(4, r1.x, c1.x, w1.x) HF_STORE(5, r1.y, c1.y, w1.y)
    HF_STORE(6, r1.z, c1.z, w1.z) HF_STORE(7, r1.w, c1.w, w1.w)
}

__global__ __launch_bounds__(256) void finalize_dc(const u64* __restrict__ dc,
                                                   float* __restrict__ dis, int n) {
    int i = blockIdx.x * blockDim.x + threadIdx.x;
    if (i < n) {
        float wsum = (float)(u32)(dc[i] & 0xFFFFFFFFu) * (1.0f / WSCALE);
        dis[i] = rsqrtf(1.0f + wsum);   // deg >= 1 (self-loop)
    }
}

// wave per node: convert (ew, r) -> (norm f32, r*64); pad bucket to mult of 16
// with zero-weight entries so the gather loop needs NO predication.
__global__ __launch_bounds__(256) void rewrite(const u64* __restrict__ dc,
                                               const float* __restrict__ dis,
                                               u32x2* __restrict__ sed, int n) {
    int wid = blockIdx.x * 4 + (threadIdx.x >> 6);
    int lane = threadIdx.x & 63;
    if (wid >= n) return;
    int cnt = (int)(dc[wid] >> 32);
    int pad = (cnt + 15) & ~15;
    if (lane >= pad) return;
    u32x2* eb = sed + (size_t)wid * CAP;
    if (lane < cnt) {
        u32x2 d = eb[lane];
        float nm = dis[wid] * __uint_as_float(d.x) * dis[(int)d.y];
        u32x2 rec; rec.x = __float_as_uint(nm); rec.y = d.y * 64u;
        eb[lane] = rec;
    } else {
        u32x2 rec; rec.x = 0u; rec.y = (u32)(wid * 64);   // zero-weight pad
        eb[lane] = rec;
    }
}

// ---------------- LDS-free MFMA GEMM: feat[M] (permuted slots) = A @ Wc^T ------
// No __shared__, no barriers. Fragments loaded straight from L2; C/D stored
// directly in the permuted slot layout (one u32 = half2 per lane per row).
// A_F16 path reads the SAME permuted layout: a true-order 8-channel k-group
// (cidx) lives in 8 consecutive u32 slots base=(cidx>>2)*16+(cidx&1)*8, in the
// (cidx>>1)&1 half of each u32 (verified: ch=8*cidx+j -> slot base+j).

template<bool A_F16>
__global__ __launch_bounds__(256) void gemm_nolds(const void* __restrict__ Aptr,
                                                  const f16* __restrict__ Wc,
                                                  u32* __restrict__ feat, int M) {
    const int tid = threadIdx.x;
    const int wave = tid >> 6, lane = tid & 63;
    const int m = lane & 15, kq = lane >> 4;
    const int row0 = blockIdx.x * 64;

    const f16x8* W8 = (const f16x8*)Wc;     // [128 rows][16 chunks]
    f32x4 acc[4][2] = {};

    #pragma unroll
    for (int ks = 0; ks < 4; ++ks) {
        const int cidx = ks * 4 + kq;       // 0..15
        f16x8 bfrag[2];
        #pragma unroll
        for (int cf = 0; cf < 2; ++cf)
            bfrag[cf] = W8[(wave * 32 + cf * 16 + m) * 16 + cidx];

        #pragma unroll
        for (int rf = 0; rf < 4; ++rf) {
            int row = row0 + rf * 16 + m;
            if (row >= M) row = M - 1;      // clamped loads; OOB outputs unstored
            f16x8 afrag;
            if (A_F16) {
                const u32x4* A4 = (const u32x4*)Aptr;
                int b4 = row * 16 + (cidx >> 2) * 4 + (cidx & 1) * 2;
                u32x4 qa = A4[b4], qb = A4[b4 + 1];
                u32 o0, o1, o2, o3;
                if (((cidx >> 1) & 1) == 0) {
                    o0 = (qa.x & 0xFFFFu) | (qa.y << 16);
                    o1 = (qa.z & 0xFFFFu) | (qa.w << 16);
                    o2 = (qb.x & 0xFFFFu) | (qb.y << 16);
                    o3 = (qb.z & 0xFFFFu) | (qb.w << 16);
                } else {
                    o0 = (qa.x >> 16) | (qa.y & 0xFFFF0000u);
                    o1 = (qa.z >> 16) | (qa.w & 0xFFFF0000u);
                    o2 = (qb.x >> 16) | (qb.y & 0xFFFF0000u);
                    o3 = (qb.z >> 16) | (qb.w & 0xFFFF0000u);
                }
                u32x4 pk; pk.x = o0; pk.y = o1; pk.z = o2; pk.w = o3;
                afrag = *reinterpret_cast<f16x8*>(&pk);
            } else {
                const float4* X4 = (const float4*)Aptr;
                float4 a = X4[row * 32 + cidx * 2];
                float4 b = X4[row * 32 + cidx * 2 + 1];
                f16x8 h;
                h[0] = (f16)a.x; h[1] = (f16)a.y; h[2] = (f16)a.z; h[3] = (f16)a.w;
                h[4] = (f16)b.x; h[5] = (f16)b.y; h[6] = (f16)b.z; h[7] = (f16)b.w;
                afrag = h;
            }
            #pragma unroll
            for (int cf = 0; cf < 2; ++cf)
                acc[rf][cf] = __builtin_amdgcn_mfma_f32_16x16x32_f16(
                    afrag, bfrag[cf], acc[rf][cf], 0, 0, 0);
        }
    }

    // direct permuted store: slot = wave*16+m, u32 = half2(cf0, cf1)
    #pragma unroll
    for (int rf = 0; rf < 4; ++rf)
        #pragma unroll
        for (int r = 0; r < 4; ++r) {
            int row = row0 + rf * 16 + kq * 4 + r;
            if (row < M) {
                __half2 p = __floats2half2_rn(acc[rf][0][r], acc[rf][1][r]);
                feat[row * 64 + wave * 16 + m] = *reinterpret_cast<u32*>(&p);
            }
        }
}

// ---------------- bucket gather + fused epilogues (permuted [N][64]u32 feat) ----
// ONE wave per node; lane = slot. Zero-padded buckets -> unpredicated 16-wide
// loop; norm f32; row pre-scaled (*64). Per edge: 8B uniform + 4B random + 2 fma.

__device__ __forceinline__ void bucket_gather(const u32x2* __restrict__ eb,
                                              const u32* __restrict__ srcu,
                                              int pad, int lane,
                                              float& a0, float& a1) {
    for (int p = 0; p < pad; p += 16) {
        #pragma unroll
        for (int j = 0; j < 16; ++j) {
            u32x2 d = eb[p + j];
            float nm = __uint_as_float(d.x);
            __half2 hv = *reinterpret_cast<const __half2*>(&srcu[d.y + lane]);
            float2 v = __half22float2(hv);
            a0 += nm * v.x;
            a1 += nm * v.y;
        }
    }
}

__global__ __launch_bounds__(256) void gather_relu(const u32x2* __restrict__ sed,
                                                   const u64* __restrict__ dc,
                                                   const float* __restrict__ dis,
                                                   const u32* __restrict__ xw,   // [n][64] permuted
                                                   const float2* __restrict__ b1p,
                                                   u32* __restrict__ h, int n) { // [n][64] permuted
    int wid = blockIdx.x * 4 + (threadIdx.x >> 6);
    int lane = threadIdx.x & 63;
    if (wid >= n) return;
    int cnt = (int)(dc[wid] >> 32);
    int pad = (cnt + 15) & ~15;
    float a0 = 0.f, a1 = 0.f;
    bucket_gather(sed + (size_t)wid * CAP, xw, pad, lane, a0, a1);
    float di = dis[wid];
    float inv = di * di;   // 1/deg
    float2 xv = __half22float2(*reinterpret_cast<const __half2*>(&xw[wid * 64 + lane]));
    float2 bb = b1p[lane];
    float o0 = fmaxf(a0 + xv.x * inv + bb.x, 0.f);
    float o1 = fmaxf(a1 + xv.y * inv + bb.y, 0.f);
    __half2 p = __floats2half2_rn(o0, o1);
    h[wid * 64 + lane] = *reinterpret_cast<u32*>(&p);
}

__global__ __launch_bounds__(256) void gather_out(const u32x2* __restrict__ sed,
                                                  const u64* __restrict__ dc,
                                                  const float* __restrict__ dis,
                                                  const u32* __restrict__ hw,   // [n][64] permuted
                                                  const float* __restrict__ bmu,
                                                  const float* __restrict__ bls,
                                                  float* __restrict__ out, int n) {
    int wid = blockIdx.x * 4 + (threadIdx.x >> 6);
    int lane = threadIdx.x & 63;
    if (wid >= n) return;
    int cnt = (int)(dc[wid] >> 32);
    int pad = (cnt + 15) & ~15;
    float a0 = 0.f, a1 = 0.f;
    bucket_gather(sed + (size_t)wid * CAP, hw, pad, lane, a0, a1);
    float di = dis[wid];
    float inv = di * di;
    float2 xv = __half22float2(*reinterpret_cast<const __half2*>(&hw[wid * 64 + lane]));
    int W = lane >> 4, mm = lane & 15;
    int ch0 = W * 32 + mm;          // true concat channel (0..127)
    int ch1 = ch0 + 16;
    // channels 0..63 -> mu, 64..127 -> logstd (un-permute on store)
    if (W < 2) {
        out[(size_t)wid * 64 + ch0] = a0 + xv.x * inv + bmu[ch0];
        out[(size_t)wid * 64 + ch1] = a1 + xv.y * inv + bmu[ch1];
    } else {
        float* o2 = out + (size_t)n * 64;
        o2[(size_t)wid * 64 + (ch0 - 64)] = a0 + xv.x * inv + bls[ch0 - 64];
        o2[(size_t)wid * 64 + (ch1 - 64)] = a1 + xv.y * inv + bls[ch1 - 64];
    }
}

extern "C" void kernel_launch(void* const* d_in, const int* in_sizes, int n_in,
                              void* d_out, int out_size, void* d_ws, size_t ws_size,
                              hipStream_t stream) {
    const float* x   = (const float*)d_in[0];
    const int*   ei  = (const int*)d_in[1];
    const float* ew  = (const float*)d_in[2];
    const float* W1  = (const float*)d_in[3];
    const float* b1  = (const float*)d_in[4];
    const float* Wmu = (const float*)d_in[5];
    const float* bmu = (const float*)d_in[6];
    const float* Wls = (const float*)d_in[7];
    const float* bls = (const float*)d_in[8];
    float* out = (float*)d_out;

    // workspace layout (u32 units; bases 16B-aligned)
    float*  dis  = (float*)d_ws;                     // 50000
    u64*    dc   = (u64*)((u32*)d_ws + 50000);       // 50000 u64
    u32x2*  sed  = (u32x2*)((u32*)d_ws + 150000);    // N*CAP u32x2 (25.6 MB)
    float2* b1p  = (float2*)((u32*)d_ws + 6550000);  // 64 float2
    f16*    Wc1  = (f16*)((u32*)d_ws + 6550128);     // 16384 f16
    f16*    Wc2  = (f16*)((u32*)d_ws + 6558320);     // 16384 f16
    u32*    Abuf = (u32*)d_ws + 6566512;             // [N][64] u32 (xw -> hw)
    u32*    Hbuf = (u32*)d_ws + 9766512;             // [N][64] u32 (h)

    const int N = N_NODES, E = N_EDGES;
    const int NB = (N + 255) / 256;   // 196
    const int WB = (N + 3) / 4;       // wave-per-node kernels

    prep<<<NB, 256, 0, stream>>>(W1, Wmu, Wls, b1, Wc1, Wc2, b1p, dc, N);
    hist_fill8<<<(E / 8 + 255) / 256, 256, 0, stream>>>(ei, ew, dc, sed, E);
    finalize_dc<<<NB, 256, 0, stream>>>(dc, dis, N);
    rewrite<<<WB, 256, 0, stream>>>(dc, dis, sed, N);

    // layer 1
    gemm_nolds<false><<<(N + 63) / 64, 256, 0, stream>>>(x, Wc1, Abuf, N);
    gather_relu<<<WB, 256, 0, stream>>>(sed, dc, dis, Abuf, b1p, Hbuf, N);

    // layer 2 (mu‖logstd in one GEMM)
    gemm_nolds<true><<<(N + 63) / 64, 256, 0, stream>>>(Hbuf, Wc2, Abuf, N);
    gather_out<<<WB, 256, 0, stream>>>(sed, dc, dis, Abuf, bmu, bls, out, N);
}

// Round 15
// 152.338 us; speedup vs baseline: 1.1376x; 1.1376x over previous
//
#include <hip/hip_runtime.h>
#include <hip/hip_fp16.h>

#define N_NODES 50000
#define N_EDGES 600000
#define CAP 64   // bucket capacity per node (max degree ~40 for Poisson(12))
#define GEMM1_BLOCKS ((N_NODES + 63) / 64)   // 782

typedef _Float16 f16;
typedef f16 f16x8 __attribute__((ext_vector_type(8)));
typedef float f32x4 __attribute__((ext_vector_type(4)));
typedef unsigned int u32;
typedef unsigned long long u64;
typedef u32 u32x2 __attribute__((ext_vector_type(2)));
typedef u32 u32x4 __attribute__((ext_vector_type(4)));

#define WSCALE 33554432.0f   // 2^25

// ---------------- prep: dc init + f16 weights (one launch) ----------------

__global__ __launch_bounds__(256) void prep(const float* __restrict__ W1,
                                            const float* __restrict__ Wmu,
                                            const float* __restrict__ Wls,
                                            f16* __restrict__ Wc1,
                                            f16* __restrict__ Wc2,
                                            u64* __restrict__ dc, int n) {
    int i = blockIdx.x * 256 + threadIdx.x;
    if (i < 16384) {
        Wc1[i] = (f16)W1[i];
        Wc2[i] = (f16)((i < 8192) ? Wmu[i] : Wls[i - 8192]);
    }
    if (i < n) dc[i] = 0ULL;
}

__global__ __launch_bounds__(256) void finalize_dc(const u64* __restrict__ dc,
                                                   float* __restrict__ dis, int n) {
    int i = blockIdx.x * blockDim.x + threadIdx.x;
    if (i < n) {
        float wsum = (float)(u32)(dc[i] & 0xFFFFFFFFu) * (1.0f / WSCALE);
        dis[i] = rsqrtf(1.0f + wsum);   // deg >= 1 (self-loop)
    }
}

// wave per node: convert (ew, r) -> (norm f32, r*64); pad bucket to mult of 16
// with zero-weight entries so the gather loop needs NO predication.
__global__ __launch_bounds__(256) void rewrite(const u64* __restrict__ dc,
                                               const float* __restrict__ dis,
                                               u32x2* __restrict__ sed, int n) {
    int wid = blockIdx.x * 4 + (threadIdx.x >> 6);
    int lane = threadIdx.x & 63;
    if (wid >= n) return;
    int cnt = (int)(dc[wid] >> 32);
    int pad = (cnt + 15) & ~15;
    if (lane >= pad) return;
    u32x2* eb = sed + (size_t)wid * CAP;
    if (lane < cnt) {
        u32x2 d = eb[lane];
        float nm = dis[wid] * __uint_as_float(d.x) * dis[(int)d.y];
        u32x2 rec; rec.x = __float_as_uint(nm); rec.y = d.y * 64u;
        eb[lane] = rec;
    } else {
        u32x2 rec; rec.x = 0u; rec.y = (u32)(wid * 64);   // zero-weight pad
        eb[lane] = rec;
    }
}

// ---------------- GEMM device body (R12-proven LDS MFMA structure) ----------------

template<bool A_F16>
__device__ __forceinline__ void gemm_body(const void* __restrict__ Aptr,
                                          const f16* __restrict__ Wc,
                                          f16* __restrict__ Cout, int M, int bid,
                                          f16* sA, f16* sW) {
    const int tid = threadIdx.x;
    const int row0 = bid * 64;

    // stage W: 2048 16B chunks, 8/thread, swizzled by row&15
    {
        const u32x4* src = (const u32x4*)Wc;
        u32x4* dst = (u32x4*)sW;
        #pragma unroll
        for (int i = 0; i < 8; ++i) {
            int c = tid + i * 256;
            int r = c >> 4, ch = c & 15;
            dst[r * 16 + (ch ^ (r & 15))] = src[c];
        }
    }
    // stage A: 1024 16B f16-chunks, 4/thread
    if (A_F16) {
        const u32x4* src = (const u32x4*)Aptr;   // row-major [M][128] f16
        u32x4* dst = (u32x4*)sA;
        #pragma unroll
        for (int i = 0; i < 4; ++i) {
            int c = tid + i * 256;
            int r = c >> 4, ch = c & 15;
            int gr = row0 + r;
            u32x4 v = {};
            if (gr < M) v = src[gr * 16 + ch];
            dst[r * 16 + (ch ^ (r & 15))] = v;
        }
    } else {
        const float4* src = (const float4*)Aptr;   // fp32 x, row-major [M][128]
        u32x4* dst = (u32x4*)sA;
        #pragma unroll
        for (int i = 0; i < 4; ++i) {
            int c = tid + i * 256;
            int r = c >> 4, ch = c & 15;
            int gr = row0 + r;
            f16x8 h = {};
            if (gr < M) {
                float4 a = src[gr * 32 + ch * 2];
                float4 b = src[gr * 32 + ch * 2 + 1];
                h[0] = (f16)a.x; h[1] = (f16)a.y; h[2] = (f16)a.z; h[3] = (f16)a.w;
                h[4] = (f16)b.x; h[5] = (f16)b.y; h[6] = (f16)b.z; h[7] = (f16)b.w;
            }
            dst[r * 16 + (ch ^ (r & 15))] = *(const u32x4*)&h;
        }
    }
    __syncthreads();

    const int wave = tid >> 6, lane = tid & 63;
    const int m = lane & 15, kq = lane >> 4;
    const int wcol0 = wave * 32;

    f32x4 acc[4][2] = {};
    const f16x8* sa = (const f16x8*)sA;
    const f16x8* sw = (const f16x8*)sW;

    #pragma unroll
    for (int ks = 0; ks < 4; ++ks) {
        int cidx = ks * 4 + kq;
        f16x8 bfrag[2];
        #pragma unroll
        for (int cf = 0; cf < 2; ++cf) {
            int wr = wcol0 + cf * 16 + m;          // W row = output col
            bfrag[cf] = sw[wr * 16 + (cidx ^ m)];
        }
        #pragma unroll
        for (int rf = 0; rf < 4; ++rf) {
            int ar = rf * 16 + m;
            f16x8 afrag = sa[ar * 16 + (cidx ^ m)];
            #pragma unroll
            for (int cf = 0; cf < 2; ++cf)
                acc[rf][cf] = __builtin_amdgcn_mfma_f32_16x16x32_f16(
                    afrag, bfrag[cf], acc[rf][cf], 0, 0, 0);
        }
    }

    __syncthreads();                 // done reading sA; reuse as output tile
    #pragma unroll
    for (int rf = 0; rf < 4; ++rf)
        #pragma unroll
        for (int cf = 0; cf < 2; ++cf)
            #pragma unroll
            for (int r = 0; r < 4; ++r)
                sA[(rf * 16 + kq * 4 + r) * 128 + wcol0 + cf * 16 + m] =
                    (f16)acc[rf][cf][r];
    __syncthreads();
    {
        const u32x4* src = (const u32x4*)sA;
        u32x4* dst = (u32x4*)Cout;
        #pragma unroll
        for (int i = 0; i < 4; ++i) {
            int c = tid + i * 256;
            int r = c >> 4, ch = c & 15;
            int gr = row0 + r;
            if (gr < M) dst[gr * 16 + ch] = src[c];
        }
    }
}

// ---------------- FUSED: GEMM1 (x@W1) blocks + hist_fill4 blocks ----------------
// The two are data-independent; co-residency overlaps hist's atomic latency
// under GEMM's MFMA work.

__global__ __launch_bounds__(256) void gemm1_hist(const float* __restrict__ x,
                                                  const f16* __restrict__ Wc1,
                                                  f16* __restrict__ Cout,
                                                  const int* __restrict__ ei,
                                                  const float* __restrict__ ew,
                                                  u64* __restrict__ dc,
                                                  u32x2* __restrict__ sed,
                                                  int M, int E) {
    __shared__ f16 sA[64 * 128];
    __shared__ f16 sW[128 * 128];
    if (blockIdx.x < GEMM1_BLOCKS) {
        gemm_body<false>(x, Wc1, Cout, M, blockIdx.x, sA, sW);
        return;
    }
    // ---- hist_fill4 part: 4 consecutive edges per thread ----
    int t = (blockIdx.x - GEMM1_BLOCKS) * 256 + threadIdx.x;
    int e = 4 * t;
    if (e >= E) return;                       // E % 4 == 0 -> all 4 valid
    int4  r = *reinterpret_cast<const int4*>(ei + e);
    int4  c = *reinterpret_cast<const int4*>(ei + E + e);
    float4 w = *reinterpret_cast<const float4*>(ew + e);

    u64 old0 = 0, old1 = 0, old2 = 0, old3 = 0;
    bool k0 = r.x != c.x, k1 = r.y != c.y, k2 = r.z != c.z, k3 = r.w != c.w;
    if (k0) old0 = atomicAdd(&dc[c.x], (1ULL << 32) | (u64)(u32)__float2uint_rn(w.x * WSCALE));
    if (k1) old1 = atomicAdd(&dc[c.y], (1ULL << 32) | (u64)(u32)__float2uint_rn(w.y * WSCALE));
    if (k2) old2 = atomicAdd(&dc[c.z], (1ULL << 32) | (u64)(u32)__float2uint_rn(w.z * WSCALE));
    if (k3) old3 = atomicAdd(&dc[c.w], (1ULL << 32) | (u64)(u32)__float2uint_rn(w.w * WSCALE));

    u32x2 rec;
    if (k0) { rec.x = __float_as_uint(w.x); rec.y = (u32)r.x; sed[c.x * CAP + (u32)(old0 >> 32)] = rec; }
    if (k1) { rec.x = __float_as_uint(w.y); rec.y = (u32)r.y; sed[c.y * CAP + (u32)(old1 >> 32)] = rec; }
    if (k2) { rec.x = __float_as_uint(w.z); rec.y = (u32)r.z; sed[c.z * CAP + (u32)(old2 >> 32)] = rec; }
    if (k3) { rec.x = __float_as_uint(w.w); rec.y = (u32)r.w; sed[c.w * CAP + (u32)(old3 >> 32)] = rec; }
}

// plain GEMM wrapper for layer 2
__global__ __launch_bounds__(256) void gemm_l2(const f16* __restrict__ Aptr,
                                               const f16* __restrict__ Wc,
                                               f16* __restrict__ Cout, int M) {
    __shared__ f16 sA[64 * 128];
    __shared__ f16 sW[128 * 128];
    gemm_body<true>(Aptr, Wc, Cout, M, blockIdx.x, sA, sW);
}

// ---------------- bucket gather + fused epilogues (row-major [N][128] f16 src) ----
// ONE wave per node; lane owns 2 channels via one half2 (u32) load. Buckets are
// zero-padded to a multiple of 16 -> unpredicated 16-wide loop, norm is f32,
// row index pre-scaled. Per edge: 8B uniform ld + 4B random ld + 2 fma.

__device__ __forceinline__ void bucket_gather(const u32x2* __restrict__ eb,
                                              const u32* __restrict__ srcu,
                                              int pad, int lane,
                                              float& a0, float& a1) {
    for (int p = 0; p < pad; p += 16) {
        #pragma unroll
        for (int j = 0; j < 16; ++j) {
            u32x2 d = eb[p + j];
            float nm = __uint_as_float(d.x);
            __half2 hv = *reinterpret_cast<const __half2*>(&srcu[d.y + lane]);
            float2 v = __half22float2(hv);
            a0 += nm * v.x;
            a1 += nm * v.y;
        }
    }
}

__global__ __launch_bounds__(256) void gather_relu(const u32x2* __restrict__ sed,
                                                   const u64* __restrict__ dc,
                                                   const float* __restrict__ dis,
                                                   const f16* __restrict__ xw,  // [n][128]
                                                   const float* __restrict__ b,
                                                   f16* __restrict__ h, int n) { // [n][128]
    int wid = blockIdx.x * 4 + (threadIdx.x >> 6);
    int lane = threadIdx.x & 63;
    if (wid >= n) return;
    const u32* srcu = (const u32*)xw;
    int cnt = (int)(dc[wid] >> 32);
    int pad = (cnt + 15) & ~15;
    float a0 = 0.f, a1 = 0.f;
    bucket_gather(sed + (size_t)wid * CAP, srcu, pad, lane, a0, a1);
    float di = dis[wid];
    float inv = di * di;   // 1/deg
    float2 xv = __half22float2(*reinterpret_cast<const __half2*>(&srcu[wid * 64 + lane]));
    float2 bb = reinterpret_cast<const float2*>(b)[lane];
    float o0 = fmaxf(a0 + xv.x * inv + bb.x, 0.f);
    float o1 = fmaxf(a1 + xv.y * inv + bb.y, 0.f);
    reinterpret_cast<__half2*>(h)[wid * 64 + lane] = __floats2half2_rn(o0, o1);
}

__global__ __launch_bounds__(256) void gather_out(const u32x2* __restrict__ sed,
                                                  const u64* __restrict__ dc,
                                                  const float* __restrict__ dis,
                                                  const f16* __restrict__ hw,  // [n][128]
                                                  const float* __restrict__ bmu,
                                                  const float* __restrict__ bls,
                                                  float* __restrict__ out, int n) {
    int wid = blockIdx.x * 4 + (threadIdx.x >> 6);
    int lane = threadIdx.x & 63;
    if (wid >= n) return;
    const u32* srcu = (const u32*)hw;
    int cnt = (int)(dc[wid] >> 32);
    int pad = (cnt + 15) & ~15;
    float a0 = 0.f, a1 = 0.f;
    bucket_gather(sed + (size_t)wid * CAP, srcu, pad, lane, a0, a1);
    float di = dis[wid];
    float inv = di * di;
    float2 xv = __half22float2(*reinterpret_cast<const __half2*>(&srcu[wid * 64 + lane]));
    float2 bb = (lane < 32) ? reinterpret_cast<const float2*>(bmu)[lane]
                            : reinterpret_cast<const float2*>(bls)[lane - 32];
    float2 o = make_float2(a0 + xv.x * inv + bb.x, a1 + xv.y * inv + bb.y);
    // cols 0..63 (lanes 0..31) -> mu ; cols 64..127 (lanes 32..63) -> logstd
    if (lane < 32)
        reinterpret_cast<float2*>(out)[wid * 32 + lane] = o;
    else
        reinterpret_cast<float2*>(out + (size_t)n * 64)[wid * 32 + (lane - 32)] = o;
}

extern "C" void kernel_launch(void* const* d_in, const int* in_sizes, int n_in,
                              void* d_out, int out_size, void* d_ws, size_t ws_size,
                              hipStream_t stream) {
    const float* x   = (const float*)d_in[0];
    const int*   ei  = (const int*)d_in[1];
    const float* ew  = (const float*)d_in[2];
    const float* W1  = (const float*)d_in[3];
    const float* b1  = (const float*)d_in[4];
    const float* Wmu = (const float*)d_in[5];
    const float* bmu = (const float*)d_in[6];
    const float* Wls = (const float*)d_in[7];
    const float* bls = (const float*)d_in[8];
    float* out = (float*)d_out;

    // workspace layout (u32 units; all bases 16B-aligned)
    float* dis   = (float*)d_ws;                     // 50000 f32
    u64*   dc    = (u64*)((u32*)d_ws + 50000);       // 50000 u64
    u32x2* sed   = (u32x2*)((u32*)d_ws + 150000);    // N*CAP u32x2 (25.6 MB)
    f16*   Wc1   = (f16*)((u32*)d_ws + 6550000);     // 16384 f16
    f16*   Wc2   = (f16*)((u32*)d_ws + 6558192);     // 16384 f16
    f16*   Abuf  = (f16*)((u32*)d_ws + 6566384);     // [N][128] f16 (xw -> hw)
    f16*   Hbuf  = (f16*)((u32*)d_ws + 9766384);     // [N][128] f16 (h)

    const int N = N_NODES, E = N_EDGES;
    const int NB = (N + 255) / 256;   // 196
    const int WB = (N + 3) / 4;       // wave-per-node kernels: 4 waves/block
    const int HB = (E / 4 + 255) / 256;   // 586 hist blocks

    prep<<<NB, 256, 0, stream>>>(W1, Wmu, Wls, Wc1, Wc2, dc, N);

    // FUSED: layer-1 GEMM + bucket-CSR histogram/fill (independent work)
    gemm1_hist<<<GEMM1_BLOCKS + HB, 256, 0, stream>>>(x, Wc1, Abuf, ei, ew, dc, sed, N, E);

    finalize_dc<<<NB, 256, 0, stream>>>(dc, dis, N);
    rewrite<<<WB, 256, 0, stream>>>(dc, dis, sed, N);

    gather_relu<<<WB, 256, 0, stream>>>(sed, dc, dis, Abuf, b1, Hbuf, N);

    // layer 2 (mu‖logstd in one GEMM)
    gemm_l2<<<(N + 63) / 64, 256, 0, stream>>>(Hbuf, Wc2, Abuf, N);
    gather_out<<<WB, 256, 0, stream>>>(sed, dc, dis, Abuf, bmu, bls, out, N);
}

// Round 16
// 137.368 us; speedup vs baseline: 1.2616x; 1.1090x over previous
//
#include <hip/hip_runtime.h>
#include <hip/hip_fp16.h>

#define N_NODES 50000
#define N_EDGES 600000
#define CAP 64   // bucket capacity per node (max degree ~40 for Poisson(12))
#define GEMM1_BLOCKS ((N_NODES + 63) / 64)   // 782

typedef _Float16 f16;
typedef f16 f16x8 __attribute__((ext_vector_type(8)));
typedef float f32x4 __attribute__((ext_vector_type(4)));
typedef unsigned int u32;
typedef unsigned long long u64;
typedef u32 u32x2 __attribute__((ext_vector_type(2)));
typedef u32 u32x4 __attribute__((ext_vector_type(4)));

#define WSCALE 33554432.0f   // 2^25

// ---------------- prep: dc init + f16 weights (one launch) ----------------

__global__ __launch_bounds__(256) void prep(const float* __restrict__ W1,
                                            const float* __restrict__ Wmu,
                                            const float* __restrict__ Wls,
                                            f16* __restrict__ Wc1,
                                            f16* __restrict__ Wc2,
                                            u64* __restrict__ dc, int n) {
    int i = blockIdx.x * 256 + threadIdx.x;
    if (i < 16384) {
        Wc1[i] = (f16)W1[i];
        Wc2[i] = (f16)((i < 8192) ? Wmu[i] : Wls[i - 8192]);
    }
    if (i < n) dc[i] = 0ULL;
}

__global__ __launch_bounds__(256) void finalize_dc(const u64* __restrict__ dc,
                                                   float* __restrict__ dis, int n) {
    int i = blockIdx.x * blockDim.x + threadIdx.x;
    if (i < n) {
        float wsum = (float)(u32)(dc[i] & 0xFFFFFFFFu) * (1.0f / WSCALE);
        dis[i] = rsqrtf(1.0f + wsum);   // deg >= 1 (self-loop)
    }
}

// wave per node: convert (ew, r) -> (norm f32, r*64); pad bucket to mult of 16
// with zero-weight entries so the gather loop needs NO predication.
__global__ __launch_bounds__(256) void rewrite(const u64* __restrict__ dc,
                                               const float* __restrict__ dis,
                                               u32x2* __restrict__ sed, int n) {
    int wid = blockIdx.x * 4 + (threadIdx.x >> 6);
    int lane = threadIdx.x & 63;
    if (wid >= n) return;
    int cnt = (int)(dc[wid] >> 32);
    int pad = (cnt + 15) & ~15;
    if (lane >= pad) return;
    u32x2* eb = sed + (size_t)wid * CAP;
    if (lane < cnt) {
        u32x2 d = eb[lane];
        float nm = dis[wid] * __uint_as_float(d.x) * dis[(int)d.y];
        u32x2 rec; rec.x = __float_as_uint(nm); rec.y = d.y * 64u;
        eb[lane] = rec;
    } else {
        u32x2 rec; rec.x = 0u; rec.y = (u32)(wid * 64);   // zero-weight pad
        eb[lane] = rec;
    }
}

// ---------------- GEMM device body: sA-only LDS (16KB), W direct from L2 ------
// W has NO cross-wave reuse (each wave owns a disjoint 32-col slice), so LDS
// staging of W bought nothing; direct loads cut LDS 48->16KB (3->10 blocks/CU).
// bfrag = W chunk (row wcol0+cf*16+m, chunk cidx) — identical data to the
// swizzled-sW path (ch^m == cidx^m  =>  ch == cidx).

template<bool A_F16>
__device__ __forceinline__ void gemm_body(const void* __restrict__ Aptr,
                                          const f16* __restrict__ Wc,
                                          f16* __restrict__ Cout, int M, int bid,
                                          f16* sA) {
    const int tid = threadIdx.x;
    const int row0 = bid * 64;

    // stage A: 1024 16B f16-chunks, 4/thread, swizzled
    if (A_F16) {
        const u32x4* src = (const u32x4*)Aptr;   // row-major [M][128] f16
        u32x4* dst = (u32x4*)sA;
        #pragma unroll
        for (int i = 0; i < 4; ++i) {
            int c = tid + i * 256;
            int r = c >> 4, ch = c & 15;
            int gr = row0 + r;
            u32x4 v = {};
            if (gr < M) v = src[gr * 16 + ch];
            dst[r * 16 + (ch ^ (r & 15))] = v;
        }
    } else {
        const float4* src = (const float4*)Aptr;   // fp32 x, row-major [M][128]
        u32x4* dst = (u32x4*)sA;
        #pragma unroll
        for (int i = 0; i < 4; ++i) {
            int c = tid + i * 256;
            int r = c >> 4, ch = c & 15;
            int gr = row0 + r;
            f16x8 h = {};
            if (gr < M) {
                float4 a = src[gr * 32 + ch * 2];
                float4 b = src[gr * 32 + ch * 2 + 1];
                h[0] = (f16)a.x; h[1] = (f16)a.y; h[2] = (f16)a.z; h[3] = (f16)a.w;
                h[4] = (f16)b.x; h[5] = (f16)b.y; h[6] = (f16)b.z; h[7] = (f16)b.w;
            }
            dst[r * 16 + (ch ^ (r & 15))] = *(const u32x4*)&h;
        }
    }
    __syncthreads();

    const int wave = tid >> 6, lane = tid & 63;
    const int m = lane & 15, kq = lane >> 4;
    const int wcol0 = wave * 32;

    f32x4 acc[4][2] = {};
    const f16x8* sa = (const f16x8*)sA;
    const f16x8* W8 = (const f16x8*)Wc;    // [128 rows][16 chunks]

    #pragma unroll
    for (int ks = 0; ks < 4; ++ks) {
        int cidx = ks * 4 + kq;
        f16x8 bfrag[2];
        #pragma unroll
        for (int cf = 0; cf < 2; ++cf)
            bfrag[cf] = W8[(wcol0 + cf * 16 + m) * 16 + cidx];   // direct from L2
        #pragma unroll
        for (int rf = 0; rf < 4; ++rf) {
            int ar = rf * 16 + m;
            f16x8 afrag = sa[ar * 16 + (cidx ^ m)];
            #pragma unroll
            for (int cf = 0; cf < 2; ++cf)
                acc[rf][cf] = __builtin_amdgcn_mfma_f32_16x16x32_f16(
                    afrag, bfrag[cf], acc[rf][cf], 0, 0, 0);
        }
    }

    __syncthreads();                 // done reading sA; reuse as output tile
    #pragma unroll
    for (int rf = 0; rf < 4; ++rf)
        #pragma unroll
        for (int cf = 0; cf < 2; ++cf)
            #pragma unroll
            for (int r = 0; r < 4; ++r)
                sA[(rf * 16 + kq * 4 + r) * 128 + wcol0 + cf * 16 + m] =
                    (f16)acc[rf][cf][r];
    __syncthreads();
    {
        const u32x4* src = (const u32x4*)sA;
        u32x4* dst = (u32x4*)Cout;
        #pragma unroll
        for (int i = 0; i < 4; ++i) {
            int c = tid + i * 256;
            int r = c >> 4, ch = c & 15;
            int gr = row0 + r;
            if (gr < M) dst[gr * 16 + ch] = src[c];
        }
    }
}

// ---------------- FUSED: GEMM1 (x@W1) blocks + hist_fill4 blocks ----------------
// Independent work; 16KB LDS keeps hist blocks at high occupancy this time.

__global__ __launch_bounds__(256) void gemm1_hist(const float* __restrict__ x,
                                                  const f16* __restrict__ Wc1,
                                                  f16* __restrict__ Cout,
                                                  const int* __restrict__ ei,
                                                  const float* __restrict__ ew,
                                                  u64* __restrict__ dc,
                                                  u32x2* __restrict__ sed,
                                                  int M, int E) {
    __shared__ f16 sA[64 * 128];
    if (blockIdx.x < GEMM1_BLOCKS) {
        gemm_body<false>(x, Wc1, Cout, M, blockIdx.x, sA);
        return;
    }
    // ---- hist_fill4 part: 4 consecutive edges per thread ----
    int t = (blockIdx.x - GEMM1_BLOCKS) * 256 + threadIdx.x;
    int e = 4 * t;
    if (e >= E) return;                       // E % 4 == 0 -> all 4 valid
    int4  r = *reinterpret_cast<const int4*>(ei + e);
    int4  c = *reinterpret_cast<const int4*>(ei + E + e);
    float4 w = *reinterpret_cast<const float4*>(ew + e);

    u64 old0 = 0, old1 = 0, old2 = 0, old3 = 0;
    bool k0 = r.x != c.x, k1 = r.y != c.y, k2 = r.z != c.z, k3 = r.w != c.w;
    if (k0) old0 = atomicAdd(&dc[c.x], (1ULL << 32) | (u64)(u32)__float2uint_rn(w.x * WSCALE));
    if (k1) old1 = atomicAdd(&dc[c.y], (1ULL << 32) | (u64)(u32)__float2uint_rn(w.y * WSCALE));
    if (k2) old2 = atomicAdd(&dc[c.z], (1ULL << 32) | (u64)(u32)__float2uint_rn(w.z * WSCALE));
    if (k3) old3 = atomicAdd(&dc[c.w], (1ULL << 32) | (u64)(u32)__float2uint_rn(w.w * WSCALE));

    u32x2 rec;
    if (k0) { rec.x = __float_as_uint(w.x); rec.y = (u32)r.x; sed[c.x * CAP + (u32)(old0 >> 32)] = rec; }
    if (k1) { rec.x = __float_as_uint(w.y); rec.y = (u32)r.y; sed[c.y * CAP + (u32)(old1 >> 32)] = rec; }
    if (k2) { rec.x = __float_as_uint(w.z); rec.y = (u32)r.z; sed[c.z * CAP + (u32)(old2 >> 32)] = rec; }
    if (k3) { rec.x = __float_as_uint(w.w); rec.y = (u32)r.w; sed[c.w * CAP + (u32)(old3 >> 32)] = rec; }
}

// plain GEMM wrapper for layer 2 (also 16KB LDS now)
__global__ __launch_bounds__(256) void gemm_l2(const f16* __restrict__ Aptr,
                                               const f16* __restrict__ Wc,
                                               f16* __restrict__ Cout, int M) {
    __shared__ f16 sA[64 * 128];
    gemm_body<true>(Aptr, Wc, Cout, M, blockIdx.x, sA);
}

// ---------------- bucket gather + fused epilogues (row-major [N][128] f16 src) ----

__device__ __forceinline__ void bucket_gather(const u32x2* __restrict__ eb,
                                              const u32* __restrict__ srcu,
                                              int pad, int lane,
                                              float& a0, float& a1) {
    for (int p = 0; p < pad; p += 16) {
        #pragma unroll
        for (int j = 0; j < 16; ++j) {
            u32x2 d = eb[p + j];
            float nm = __uint_as_float(d.x);
            __half2 hv = *reinterpret_cast<const __half2*>(&srcu[d.y + lane]);
            float2 v = __half22float2(hv);
            a0 += nm * v.x;
            a1 += nm * v.y;
        }
    }
}

__global__ __launch_bounds__(256) void gather_relu(const u32x2* __restrict__ sed,
                                                   const u64* __restrict__ dc,
                                                   const float* __restrict__ dis,
                                                   const f16* __restrict__ xw,  // [n][128]
                                                   const float* __restrict__ b,
                                                   f16* __restrict__ h, int n) { // [n][128]
    int wid = blockIdx.x * 4 + (threadIdx.x >> 6);
    int lane = threadIdx.x & 63;
    if (wid >= n) return;
    const u32* srcu = (const u32*)xw;
    int cnt = (int)(dc[wid] >> 32);
    int pad = (cnt + 15) & ~15;
    float a0 = 0.f, a1 = 0.f;
    bucket_gather(sed + (size_t)wid * CAP, srcu, pad, lane, a0, a1);
    float di = dis[wid];
    float inv = di * di;   // 1/deg
    float2 xv = __half22float2(*reinterpret_cast<const __half2*>(&srcu[wid * 64 + lane]));
    float2 bb = reinterpret_cast<const float2*>(b)[lane];
    float o0 = fmaxf(a0 + xv.x * inv + bb.x, 0.f);
    float o1 = fmaxf(a1 + xv.y * inv + bb.y, 0.f);
    reinterpret_cast<__half2*>(h)[wid * 64 + lane] = __floats2half2_rn(o0, o1);
}

__global__ __launch_bounds__(256) void gather_out(const u32x2* __restrict__ sed,
                                                  const u64* __restrict__ dc,
                                                  const float* __restrict__ dis,
                                                  const f16* __restrict__ hw,  // [n][128]
                                                  const float* __restrict__ bmu,
                                                  const float* __restrict__ bls,
                                                  float* __restrict__ out, int n) {
    int wid = blockIdx.x * 4 + (threadIdx.x >> 6);
    int lane = threadIdx.x & 63;
    if (wid >= n) return;
    const u32* srcu = (const u32*)hw;
    int cnt = (int)(dc[wid] >> 32);
    int pad = (cnt + 15) & ~15;
    float a0 = 0.f, a1 = 0.f;
    bucket_gather(sed + (size_t)wid * CAP, srcu, pad, lane, a0, a1);
    float di = dis[wid];
    float inv = di * di;
    float2 xv = __half22float2(*reinterpret_cast<const __half2*>(&srcu[wid * 64 + lane]));
    float2 bb = (lane < 32) ? reinterpret_cast<const float2*>(bmu)[lane]
                            : reinterpret_cast<const float2*>(bls)[lane - 32];
    float2 o = make_float2(a0 + xv.x * inv + bb.x, a1 + xv.y * inv + bb.y);
    // cols 0..63 (lanes 0..31) -> mu ; cols 64..127 (lanes 32..63) -> logstd
    if (lane < 32)
        reinterpret_cast<float2*>(out)[wid * 32 + lane] = o;
    else
        reinterpret_cast<float2*>(out + (size_t)n * 64)[wid * 32 + (lane - 32)] = o;
}

extern "C" void kernel_launch(void* const* d_in, const int* in_sizes, int n_in,
                              void* d_out, int out_size, void* d_ws, size_t ws_size,
                              hipStream_t stream) {
    const float* x   = (const float*)d_in[0];
    const int*   ei  = (const int*)d_in[1];
    const float* ew  = (const float*)d_in[2];
    const float* W1  = (const float*)d_in[3];
    const float* b1  = (const float*)d_in[4];
    const float* Wmu = (const float*)d_in[5];
    const float* bmu = (const float*)d_in[6];
    const float* Wls = (const float*)d_in[7];
    const float* bls = (const float*)d_in[8];
    float* out = (float*)d_out;

    // workspace layout (u32 units; all bases 16B-aligned)
    float* dis   = (float*)d_ws;                     // 50000 f32
    u64*   dc    = (u64*)((u32*)d_ws + 50000);       // 50000 u64
    u32x2* sed   = (u32x2*)((u32*)d_ws + 150000);    // N*CAP u32x2 (25.6 MB)
    f16*   Wc1   = (f16*)((u32*)d_ws + 6550000);     // 16384 f16
    f16*   Wc2   = (f16*)((u32*)d_ws + 6558192);     // 16384 f16
    f16*   Abuf  = (f16*)((u32*)d_ws + 6566384);     // [N][128] f16 (xw -> hw)
    f16*   Hbuf  = (f16*)((u32*)d_ws + 9766384);     // [N][128] f16 (h)

    const int N = N_NODES, E = N_EDGES;
    const int NB = (N + 255) / 256;   // 196
    const int WB = (N + 3) / 4;       // wave-per-node kernels: 4 waves/block
    const int HB = (E / 4 + 255) / 256;   // 586 hist blocks

    prep<<<NB, 256, 0, stream>>>(W1, Wmu, Wls, Wc1, Wc2, dc, N);

    // FUSED: layer-1 GEMM + bucket-CSR histogram/fill (independent work)
    gemm1_hist<<<GEMM1_BLOCKS + HB, 256, 0, stream>>>(x, Wc1, Abuf, ei, ew, dc, sed, N, E);

    finalize_dc<<<NB, 256, 0, stream>>>(dc, dis, N);
    rewrite<<<WB, 256, 0, stream>>>(dc, dis, sed, N);

    gather_relu<<<WB, 256, 0, stream>>>(sed, dc, dis, Abuf, b1, Hbuf, N);

    // layer 2 (mu‖logstd in one GEMM)
    gemm_l2<<<(N + 63) / 64, 256, 0, stream>>>(Hbuf, Wc2, Abuf, N);
    gather_out<<<WB, 256, 0, stream>>>(sed, dc, dis, Abuf, bmu, bls, out, N);
}

// Round 17
// 125.372 us; speedup vs baseline: 1.3823x; 1.0957x over previous
//
#include <hip/hip_runtime.h>
#include <hip/hip_fp16.h>

#define N_NODES 50000
#define N_EDGES 600000
#define CAP 64   // bucket capacity per node (max degree ~40 for Poisson(12))
#define HIST_BLOCKS ((N_EDGES / 4 + 255) / 256)   // 586, first in fused grid
#define GEMM1_BLOCKS ((N_NODES + 63) / 64)        // 782

typedef _Float16 f16;
typedef f16 f16x8 __attribute__((ext_vector_type(8)));
typedef float f32x4 __attribute__((ext_vector_type(4)));
typedef unsigned int u32;
typedef unsigned long long u64;
typedef u32 u32x2 __attribute__((ext_vector_type(2)));
typedef u32 u32x4 __attribute__((ext_vector_type(4)));

#define WSCALE 33554432.0f   // 2^25

__device__ __forceinline__ float wsum_of(u64 dcv) {
    return (float)(u32)(dcv & 0xFFFFFFFFu) * (1.0f / WSCALE);
}

// ---------------- prep: dc init + f16 weights (one launch) ----------------

__global__ __launch_bounds__(256) void prep(const float* __restrict__ W1,
                                            const float* __restrict__ Wmu,
                                            const float* __restrict__ Wls,
                                            f16* __restrict__ Wc1,
                                            f16* __restrict__ Wc2,
                                            u64* __restrict__ dc, int n) {
    int i = blockIdx.x * 256 + threadIdx.x;
    if (i < 16384) {
        Wc1[i] = (f16)W1[i];
        Wc2[i] = (f16)((i < 8192) ? Wmu[i] : Wls[i - 8192]);
    }
    if (i < n) dc[i] = 0ULL;
}

// wave per node: expand 4B (f16 w | row) records -> 8B (f32 norm, row*64),
// computing dis inline from dc; pad bucket to mult of 16 with zero entries.
__global__ __launch_bounds__(256) void rewrite(const u64* __restrict__ dc,
                                               const u32* __restrict__ sed4,
                                               u32x2* __restrict__ sed8, int n) {
    int wid = blockIdx.x * 4 + (threadIdx.x >> 6);
    int lane = threadIdx.x & 63;
    if (wid >= n) return;
    u64 dcw = dc[wid];
    int cnt = (int)(dcw >> 32);
    int pad = (cnt + 15) & ~15;
    if (lane >= pad) return;
    u32x2 rec;
    if (lane < cnt) {
        u32 d4 = sed4[(size_t)wid * CAP + lane];
        int r = (int)(d4 & 0xFFFFu);
        float w = __half2float(__ushort_as_half((unsigned short)(d4 >> 16)));
        float dis_own = rsqrtf(1.0f + wsum_of(dcw));
        float dis_r   = rsqrtf(1.0f + wsum_of(dc[r]));
        rec.x = __float_as_uint(dis_own * w * dis_r);
        rec.y = (u32)r * 64u;
    } else {
        rec.x = 0u; rec.y = (u32)(wid * 64);   // zero-weight pad
    }
    sed8[(size_t)wid * CAP + lane] = rec;
}

// ---------------- GEMM device body: sA-only LDS (16KB), W direct from L2 ------

template<bool A_F16>
__device__ __forceinline__ void gemm_body(const void* __restrict__ Aptr,
                                          const f16* __restrict__ Wc,
                                          f16* __restrict__ Cout, int M, int bid,
                                          f16* sA) {
    const int tid = threadIdx.x;
    const int row0 = bid * 64;

    if (A_F16) {
        const u32x4* src = (const u32x4*)Aptr;   // row-major [M][128] f16
        u32x4* dst = (u32x4*)sA;
        #pragma unroll
        for (int i = 0; i < 4; ++i) {
            int c = tid + i * 256;
            int r = c >> 4, ch = c & 15;
            int gr = row0 + r;
            u32x4 v = {};
            if (gr < M) v = src[gr * 16 + ch];
            dst[r * 16 + (ch ^ (r & 15))] = v;
        }
    } else {
        const float4* src = (const float4*)Aptr;   // fp32 x, row-major [M][128]
        u32x4* dst = (u32x4*)sA;
        #pragma unroll
        for (int i = 0; i < 4; ++i) {
            int c = tid + i * 256;
            int r = c >> 4, ch = c & 15;
            int gr = row0 + r;
            f16x8 h = {};
            if (gr < M) {
                float4 a = src[gr * 32 + ch * 2];
                float4 b = src[gr * 32 + ch * 2 + 1];
                h[0] = (f16)a.x; h[1] = (f16)a.y; h[2] = (f16)a.z; h[3] = (f16)a.w;
                h[4] = (f16)b.x; h[5] = (f16)b.y; h[6] = (f16)b.z; h[7] = (f16)b.w;
            }
            dst[r * 16 + (ch ^ (r & 15))] = *(const u32x4*)&h;
        }
    }
    __syncthreads();

    const int wave = tid >> 6, lane = tid & 63;
    const int m = lane & 15, kq = lane >> 4;
    const int wcol0 = wave * 32;

    f32x4 acc[4][2] = {};
    const f16x8* sa = (const f16x8*)sA;
    const f16x8* W8 = (const f16x8*)Wc;    // [128 rows][16 chunks]

    #pragma unroll
    for (int ks = 0; ks < 4; ++ks) {
        int cidx = ks * 4 + kq;
        f16x8 bfrag[2];
        #pragma unroll
        for (int cf = 0; cf < 2; ++cf)
            bfrag[cf] = W8[(wcol0 + cf * 16 + m) * 16 + cidx];   // direct from L2
        #pragma unroll
        for (int rf = 0; rf < 4; ++rf) {
            int ar = rf * 16 + m;
            f16x8 afrag = sa[ar * 16 + (cidx ^ m)];
            #pragma unroll
            for (int cf = 0; cf < 2; ++cf)
                acc[rf][cf] = __builtin_amdgcn_mfma_f32_16x16x32_f16(
                    afrag, bfrag[cf], acc[rf][cf], 0, 0, 0);
        }
    }

    __syncthreads();                 // done reading sA; reuse as output tile
    #pragma unroll
    for (int rf = 0; rf < 4; ++rf)
        #pragma unroll
        for (int cf = 0; cf < 2; ++cf)
            #pragma unroll
            for (int r = 0; r < 4; ++r)
                sA[(rf * 16 + kq * 4 + r) * 128 + wcol0 + cf * 16 + m] =
                    (f16)acc[rf][cf][r];
    __syncthreads();
    {
        const u32x4* src = (const u32x4*)sA;
        u32x4* dst = (u32x4*)Cout;
        #pragma unroll
        for (int i = 0; i < 4; ++i) {
            int c = tid + i * 256;
            int r = c >> 4, ch = c & 15;
            int gr = row0 + r;
            if (gr < M) dst[gr * 16 + ch] = src[c];
        }
    }
}

// ---------------- FUSED: hist_fill4 blocks (FIRST: critical path) + GEMM1 ------
// hist stores 4B packed records (f16 w | row) -> ~half the dirtied lines.

__global__ __launch_bounds__(256) void gemm1_hist(const float* __restrict__ x,
                                                  const f16* __restrict__ Wc1,
                                                  f16* __restrict__ Cout,
                                                  const int* __restrict__ ei,
                                                  const float* __restrict__ ew,
                                                  u64* __restrict__ dc,
                                                  u32* __restrict__ sed4,
                                                  int M, int E) {
    __shared__ f16 sA[64 * 128];
    if (blockIdx.x >= HIST_BLOCKS) {
        gemm_body<false>(x, Wc1, Cout, M, blockIdx.x - HIST_BLOCKS, sA);
        return;
    }
    // ---- hist_fill4 part: 4 consecutive edges per thread ----
    int t = blockIdx.x * 256 + threadIdx.x;
    int e = 4 * t;
    if (e >= E) return;                       // E % 4 == 0 -> all 4 valid
    int4  r = *reinterpret_cast<const int4*>(ei + e);
    int4  c = *reinterpret_cast<const int4*>(ei + E + e);
    float4 w = *reinterpret_cast<const float4*>(ew + e);

    u64 old0 = 0, old1 = 0, old2 = 0, old3 = 0;
    bool k0 = r.x != c.x, k1 = r.y != c.y, k2 = r.z != c.z, k3 = r.w != c.w;
    if (k0) old0 = atomicAdd(&dc[c.x], (1ULL << 32) | (u64)(u32)__float2uint_rn(w.x * WSCALE));
    if (k1) old1 = atomicAdd(&dc[c.y], (1ULL << 32) | (u64)(u32)__float2uint_rn(w.y * WSCALE));
    if (k2) old2 = atomicAdd(&dc[c.z], (1ULL << 32) | (u64)(u32)__float2uint_rn(w.z * WSCALE));
    if (k3) old3 = atomicAdd(&dc[c.w], (1ULL << 32) | (u64)(u32)__float2uint_rn(w.w * WSCALE));

    #define PK4(ww, rr) ((((u32)__half_as_ushort(__float2half(ww))) << 16) | (u32)(rr))
    if (k0) sed4[(size_t)c.x * CAP + (u32)(old0 >> 32)] = PK4(w.x, r.x);
    if (k1) sed4[(size_t)c.y * CAP + (u32)(old1 >> 32)] = PK4(w.y, r.y);
    if (k2) sed4[(size_t)c.z * CAP + (u32)(old2 >> 32)] = PK4(w.z, r.z);
    if (k3) sed4[(size_t)c.w * CAP + (u32)(old3 >> 32)] = PK4(w.w, r.w);
    #undef PK4
}

// plain GEMM wrapper for layer 2
__global__ __launch_bounds__(256) void gemm_l2(const f16* __restrict__ Aptr,
                                               const f16* __restrict__ Wc,
                                               f16* __restrict__ Cout, int M) {
    __shared__ f16 sA[64 * 128];
    gemm_body<true>(Aptr, Wc, Cout, M, blockIdx.x, sA);
}

// ---------------- bucket gather + fused epilogues (row-major [N][128] f16 src) ----

__device__ __forceinline__ void bucket_gather(const u32x2* __restrict__ eb,
                                              const u32* __restrict__ srcu,
                                              int pad, int lane,
                                              float& a0, float& a1) {
    for (int p = 0; p < pad; p += 16) {
        #pragma unroll
        for (int j = 0; j < 16; ++j) {
            u32x2 d = eb[p + j];
            float nm = __uint_as_float(d.x);
            __half2 hv = *reinterpret_cast<const __half2*>(&srcu[d.y + lane]);
            float2 v = __half22float2(hv);
            a0 += nm * v.x;
            a1 += nm * v.y;
        }
    }
}

__global__ __launch_bounds__(256) void gather_relu(const u32x2* __restrict__ sed8,
                                                   const u64* __restrict__ dc,
                                                   const f16* __restrict__ xw,  // [n][128]
                                                   const float* __restrict__ b,
                                                   f16* __restrict__ h, int n) { // [n][128]
    int wid = blockIdx.x * 4 + (threadIdx.x >> 6);
    int lane = threadIdx.x & 63;
    if (wid >= n) return;
    const u32* srcu = (const u32*)xw;
    u64 dcw = dc[wid];
    int cnt = (int)(dcw >> 32);
    int pad = (cnt + 15) & ~15;
    float a0 = 0.f, a1 = 0.f;
    bucket_gather(sed8 + (size_t)wid * CAP, srcu, pad, lane, a0, a1);
    float inv = 1.0f / (1.0f + wsum_of(dcw));   // 1/deg
    float2 xv = __half22float2(*reinterpret_cast<const __half2*>(&srcu[wid * 64 + lane]));
    float2 bb = reinterpret_cast<const float2*>(b)[lane];
    float o0 = fmaxf(a0 + xv.x * inv + bb.x, 0.f);
    float o1 = fmaxf(a1 + xv.y * inv + bb.y, 0.f);
    reinterpret_cast<__half2*>(h)[wid * 64 + lane] = __floats2half2_rn(o0, o1);
}

__global__ __launch_bounds__(256) void gather_out(const u32x2* __restrict__ sed8,
                                                  const u64* __restrict__ dc,
                                                  const f16* __restrict__ hw,  // [n][128]
                                                  const float* __restrict__ bmu,
                                                  const float* __restrict__ bls,
                                                  float* __restrict__ out, int n) {
    int wid = blockIdx.x * 4 + (threadIdx.x >> 6);
    int lane = threadIdx.x & 63;
    if (wid >= n) return;
    const u32* srcu = (const u32*)hw;
    u64 dcw = dc[wid];
    int cnt = (int)(dcw >> 32);
    int pad = (cnt + 15) & ~15;
    float a0 = 0.f, a1 = 0.f;
    bucket_gather(sed8 + (size_t)wid * CAP, srcu, pad, lane, a0, a1);
    float inv = 1.0f / (1.0f + wsum_of(dcw));
    float2 xv = __half22float2(*reinterpret_cast<const __half2*>(&srcu[wid * 64 + lane]));
    float2 bb = (lane < 32) ? reinterpret_cast<const float2*>(bmu)[lane]
                            : reinterpret_cast<const float2*>(bls)[lane - 32];
    float2 o = make_float2(a0 + xv.x * inv + bb.x, a1 + xv.y * inv + bb.y);
    // cols 0..63 (lanes 0..31) -> mu ; cols 64..127 (lanes 32..63) -> logstd
    if (lane < 32)
        reinterpret_cast<float2*>(out)[wid * 32 + lane] = o;
    else
        reinterpret_cast<float2*>(out + (size_t)n * 64)[wid * 32 + (lane - 32)] = o;
}

extern "C" void kernel_launch(void* const* d_in, const int* in_sizes, int n_in,
                              void* d_out, int out_size, void* d_ws, size_t ws_size,
                              hipStream_t stream) {
    const float* x   = (const float*)d_in[0];
    const int*   ei  = (const int*)d_in[1];
    const float* ew  = (const float*)d_in[2];
    const float* W1  = (const float*)d_in[3];
    const float* b1  = (const float*)d_in[4];
    const float* Wmu = (const float*)d_in[5];
    const float* bmu = (const float*)d_in[6];
    const float* Wls = (const float*)d_in[7];
    const float* bls = (const float*)d_in[8];
    float* out = (float*)d_out;

    // workspace layout (u32 units; all bases 16B-aligned).
    // sed4 ALIASES Hbuf: sed4 dead before gather_relu writes h.
    u64*   dc    = (u64*)d_ws;                       // 50000 u64 (100000 u32)
    u32x2* sed8  = (u32x2*)((u32*)d_ws + 100000);    // N*CAP u32x2 (25.6 MB)
    f16*   Wc1   = (f16*)((u32*)d_ws + 6500000);     // 16384 f16
    f16*   Wc2   = (f16*)((u32*)d_ws + 6508192);     // 16384 f16
    f16*   Abuf  = (f16*)((u32*)d_ws + 6516384);     // [N][128] f16 (xw -> hw)
    u32*   HbufU = (u32*)d_ws + 9716384;             // [N][64] u32 region
    f16*   Hbuf  = (f16*)HbufU;                      //   = h  [N][128] f16
    u32*   sed4  = HbufU;                            //   = 4B records (pre-h)

    const int N = N_NODES, E = N_EDGES;
    const int NB = (N + 255) / 256;   // 196
    const int WB = (N + 3) / 4;       // wave-per-node kernels: 4 waves/block

    prep<<<NB, 256, 0, stream>>>(W1, Wmu, Wls, Wc1, Wc2, dc, N);

    // FUSED: bucket-CSR histogram/fill (first) + layer-1 GEMM
    gemm1_hist<<<HIST_BLOCKS + GEMM1_BLOCKS, 256, 0, stream>>>(
        x, Wc1, Abuf, ei, ew, dc, sed4, N, E);

    rewrite<<<WB, 256, 0, stream>>>(dc, sed4, sed8, N);

    gather_relu<<<WB, 256, 0, stream>>>(sed8, dc, Abuf, b1, Hbuf, N);

    // layer 2 (mu‖logstd in one GEMM)
    gemm_l2<<<(N + 63) / 64, 256, 0, stream>>>(Hbuf, Wc2, Abuf, N);
    gather_out<<<WB, 256, 0, stream>>>(sed8, dc, Abuf, bmu, bls, out, N);
}

// Round 18
// 124.394 us; speedup vs baseline: 1.3932x; 1.0079x over previous
//
#include <hip/hip_runtime.h>
#include <hip/hip_fp16.h>

#define N_NODES 50000
#define N_EDGES 600000
#define CAP 64   // bucket capacity per node (max degree ~40 for Poisson(12))
#define GEMM1_BLOCKS ((N_NODES + 63) / 64)        // 782 (first in fused grid)
#define HIST_BLOCKS ((N_EDGES / 4 + 255) / 256)   // 586

typedef _Float16 f16;
typedef f16 f16x8 __attribute__((ext_vector_type(8)));
typedef float f32x4 __attribute__((ext_vector_type(4)));
typedef unsigned int u32;
typedef unsigned long long u64;
typedef u32 u32x2 __attribute__((ext_vector_type(2)));
typedef u32 u32x4 __attribute__((ext_vector_type(4)));

#define WSCALE 33554432.0f   // 2^25

__device__ __forceinline__ float wsum_of(u64 dcv) {
    return (float)(u32)(dcv & 0xFFFFFFFFu) * (1.0f / WSCALE);
}

// ---------------- prep: dc init + f16 weights (one launch) ----------------

__global__ __launch_bounds__(256) void prep(const float* __restrict__ W1,
                                            const float* __restrict__ Wmu,
                                            const float* __restrict__ Wls,
                                            f16* __restrict__ Wc1,
                                            f16* __restrict__ Wc2,
                                            u64* __restrict__ dc, int n) {
    int i = blockIdx.x * 256 + threadIdx.x;
    if (i < 16384) {
        Wc1[i] = (f16)W1[i];
        Wc2[i] = (f16)((i < 8192) ? Wmu[i] : Wls[i - 8192]);
    }
    if (i < n) dc[i] = 0ULL;
}

// wave per node: IN-PLACE convert (f32 w, r) -> (f32 norm, r*64), dis inline
// from dc; pad bucket to mult of 16 with zero-weight entries (unpredicated gather).
__global__ __launch_bounds__(256) void rewrite(const u64* __restrict__ dc,
                                               u32x2* __restrict__ sed8, int n) {
    int wid = blockIdx.x * 4 + (threadIdx.x >> 6);
    int lane = threadIdx.x & 63;
    if (wid >= n) return;
    u64 dcw = dc[wid];
    int cnt = (int)(dcw >> 32);
    int pad = (cnt + 15) & ~15;
    if (lane >= pad) return;
    u32x2* eb = sed8 + (size_t)wid * CAP;
    u32x2 rec;
    if (lane < cnt) {
        u32x2 d = eb[lane];
        int r = (int)d.y;
        float w = __uint_as_float(d.x);
        float dis_own = rsqrtf(1.0f + wsum_of(dcw));
        float dis_r   = rsqrtf(1.0f + wsum_of(dc[r]));
        rec.x = __float_as_uint(dis_own * w * dis_r);
        rec.y = (u32)r * 64u;
    } else {
        rec.x = 0u; rec.y = (u32)(wid * 64);   // zero-weight pad
    }
    eb[lane] = rec;
}

// ---------------- GEMM device body: sA-only LDS (16KB), W direct from L2 ------

template<bool A_F16>
__device__ __forceinline__ void gemm_body(const void* __restrict__ Aptr,
                                          const f16* __restrict__ Wc,
                                          f16* __restrict__ Cout, int M, int bid,
                                          f16* sA) {
    const int tid = threadIdx.x;
    const int row0 = bid * 64;

    if (A_F16) {
        const u32x4* src = (const u32x4*)Aptr;   // row-major [M][128] f16
        u32x4* dst = (u32x4*)sA;
        #pragma unroll
        for (int i = 0; i < 4; ++i) {
            int c = tid + i * 256;
            int r = c >> 4, ch = c & 15;
            int gr = row0 + r;
            u32x4 v = {};
            if (gr < M) v = src[gr * 16 + ch];
            dst[r * 16 + (ch ^ (r & 15))] = v;
        }
    } else {
        const float4* src = (const float4*)Aptr;   // fp32 x, row-major [M][128]
        u32x4* dst = (u32x4*)sA;
        #pragma unroll
        for (int i = 0; i < 4; ++i) {
            int c = tid + i * 256;
            int r = c >> 4, ch = c & 15;
            int gr = row0 + r;
            f16x8 h = {};
            if (gr < M) {
                float4 a = src[gr * 32 + ch * 2];
                float4 b = src[gr * 32 + ch * 2 + 1];
                h[0] = (f16)a.x; h[1] = (f16)a.y; h[2] = (f16)a.z; h[3] = (f16)a.w;
                h[4] = (f16)b.x; h[5] = (f16)b.y; h[6] = (f16)b.z; h[7] = (f16)b.w;
            }
            dst[r * 16 + (ch ^ (r & 15))] = *(const u32x4*)&h;
        }
    }
    __syncthreads();

    const int wave = tid >> 6, lane = tid & 63;
    const int m = lane & 15, kq = lane >> 4;
    const int wcol0 = wave * 32;

    f32x4 acc[4][2] = {};
    const f16x8* sa = (const f16x8*)sA;
    const f16x8* W8 = (const f16x8*)Wc;    // [128 rows][16 chunks]

    #pragma unroll
    for (int ks = 0; ks < 4; ++ks) {
        int cidx = ks * 4 + kq;
        f16x8 bfrag[2];
        #pragma unroll
        for (int cf = 0; cf < 2; ++cf)
            bfrag[cf] = W8[(wcol0 + cf * 16 + m) * 16 + cidx];   // direct from L2
        #pragma unroll
        for (int rf = 0; rf < 4; ++rf) {
            int ar = rf * 16 + m;
            f16x8 afrag = sa[ar * 16 + (cidx ^ m)];
            #pragma unroll
            for (int cf = 0; cf < 2; ++cf)
                acc[rf][cf] = __builtin_amdgcn_mfma_f32_16x16x32_f16(
                    afrag, bfrag[cf], acc[rf][cf], 0, 0, 0);
        }
    }

    __syncthreads();                 // done reading sA; reuse as output tile
    #pragma unroll
    for (int rf = 0; rf < 4; ++rf)
        #pragma unroll
        for (int cf = 0; cf < 2; ++cf)
            #pragma unroll
            for (int r = 0; r < 4; ++r)
                sA[(rf * 16 + kq * 4 + r) * 128 + wcol0 + cf * 16 + m] =
                    (f16)acc[rf][cf][r];
    __syncthreads();
    {
        const u32x4* src = (const u32x4*)sA;
        u32x4* dst = (u32x4*)Cout;
        #pragma unroll
        for (int i = 0; i < 4; ++i) {
            int c = tid + i * 256;
            int r = c >> 4, ch = c & 15;
            int gr = row0 + r;
            if (gr < M) dst[gr * 16 + ch] = src[c];
        }
    }
}

// ---------------- FUSED: GEMM1 blocks first + hist_fill4 blocks ----------------
// hist stores 8B {f32 w, u32 r} records (R15-measured-fastest form).

__global__ __launch_bounds__(256) void gemm1_hist(const float* __restrict__ x,
                                                  const f16* __restrict__ Wc1,
                                                  f16* __restrict__ Cout,
                                                  const int* __restrict__ ei,
                                                  const float* __restrict__ ew,
                                                  u64* __restrict__ dc,
                                                  u32x2* __restrict__ sed8,
                                                  int M, int E) {
    __shared__ f16 sA[64 * 128];
    if (blockIdx.x < GEMM1_BLOCKS) {
        gemm_body<false>(x, Wc1, Cout, M, blockIdx.x, sA);
        return;
    }
    // ---- hist_fill4 part: 4 consecutive edges per thread ----
    int t = (blockIdx.x - GEMM1_BLOCKS) * 256 + threadIdx.x;
    int e = 4 * t;
    if (e >= E) return;                       // E % 4 == 0 -> all 4 valid
    int4  r = *reinterpret_cast<const int4*>(ei + e);
    int4  c = *reinterpret_cast<const int4*>(ei + E + e);
    float4 w = *reinterpret_cast<const float4*>(ew + e);

    u64 old0 = 0, old1 = 0, old2 = 0, old3 = 0;
    bool k0 = r.x != c.x, k1 = r.y != c.y, k2 = r.z != c.z, k3 = r.w != c.w;
    if (k0) old0 = atomicAdd(&dc[c.x], (1ULL << 32) | (u64)(u32)__float2uint_rn(w.x * WSCALE));
    if (k1) old1 = atomicAdd(&dc[c.y], (1ULL << 32) | (u64)(u32)__float2uint_rn(w.y * WSCALE));
    if (k2) old2 = atomicAdd(&dc[c.z], (1ULL << 32) | (u64)(u32)__float2uint_rn(w.z * WSCALE));
    if (k3) old3 = atomicAdd(&dc[c.w], (1ULL << 32) | (u64)(u32)__float2uint_rn(w.w * WSCALE));

    u32x2 rec;
    if (k0) { rec.x = __float_as_uint(w.x); rec.y = (u32)r.x; sed8[(size_t)c.x * CAP + (u32)(old0 >> 32)] = rec; }
    if (k1) { rec.x = __float_as_uint(w.y); rec.y = (u32)r.y; sed8[(size_t)c.y * CAP + (u32)(old1 >> 32)] = rec; }
    if (k2) { rec.x = __float_as_uint(w.z); rec.y = (u32)r.z; sed8[(size_t)c.z * CAP + (u32)(old2 >> 32)] = rec; }
    if (k3) { rec.x = __float_as_uint(w.w); rec.y = (u32)r.w; sed8[(size_t)c.w * CAP + (u32)(old3 >> 32)] = rec; }
}

// plain GEMM wrapper for layer 2
__global__ __launch_bounds__(256) void gemm_l2(const f16* __restrict__ Aptr,
                                               const f16* __restrict__ Wc,
                                               f16* __restrict__ Cout, int M) {
    __shared__ f16 sA[64 * 128];
    gemm_body<true>(Aptr, Wc, Cout, M, blockIdx.x, sA);
}

// ---------------- bucket gather + fused epilogues (row-major [N][128] f16 src) ----

__device__ __forceinline__ void bucket_gather(const u32x2* __restrict__ eb,
                                              const u32* __restrict__ srcu,
                                              int pad, int lane,
                                              float& a0, float& a1) {
    for (int p = 0; p < pad; p += 16) {
        #pragma unroll
        for (int j = 0; j < 16; ++j) {
            u32x2 d = eb[p + j];
            float nm = __uint_as_float(d.x);
            __half2 hv = *reinterpret_cast<const __half2*>(&srcu[d.y + lane]);
            float2 v = __half22float2(hv);
            a0 += nm * v.x;
            a1 += nm * v.y;
        }
    }
}

__global__ __launch_bounds__(256) void gather_relu(const u32x2* __restrict__ sed8,
                                                   const u64* __restrict__ dc,
                                                   const f16* __restrict__ xw,  // [n][128]
                                                   const float* __restrict__ b,
                                                   f16* __restrict__ h, int n) { // [n][128]
    int wid = blockIdx.x * 4 + (threadIdx.x >> 6);
    int lane = threadIdx.x & 63;
    if (wid >= n) return;
    const u32* srcu = (const u32*)xw;
    u64 dcw = dc[wid];
    int cnt = (int)(dcw >> 32);
    int pad = (cnt + 15) & ~15;
    float a0 = 0.f, a1 = 0.f;
    bucket_gather(sed8 + (size_t)wid * CAP, srcu, pad, lane, a0, a1);
    float inv = 1.0f / (1.0f + wsum_of(dcw));   // 1/deg
    float2 xv = __half22float2(*reinterpret_cast<const __half2*>(&srcu[wid * 64 + lane]));
    float2 bb = reinterpret_cast<const float2*>(b)[lane];
    float o0 = fmaxf(a0 + xv.x * inv + bb.x, 0.f);
    float o1 = fmaxf(a1 + xv.y * inv + bb.y, 0.f);
    reinterpret_cast<__half2*>(h)[wid * 64 + lane] = __floats2half2_rn(o0, o1);
}

__global__ __launch_bounds__(256) void gather_out(const u32x2* __restrict__ sed8,
                                                  const u64* __restrict__ dc,
                                                  const f16* __restrict__ hw,  // [n][128]
                                                  const float* __restrict__ bmu,
                                                  const float* __restrict__ bls,
                                                  float* __restrict__ out, int n) {
    int wid = blockIdx.x * 4 + (threadIdx.x >> 6);
    int lane = threadIdx.x & 63;
    if (wid >= n) return;
    const u32* srcu = (const u32*)hw;
    u64 dcw = dc[wid];
    int cnt = (int)(dcw >> 32);
    int pad = (cnt + 15) & ~15;
    float a0 = 0.f, a1 = 0.f;
    bucket_gather(sed8 + (size_t)wid * CAP, srcu, pad, lane, a0, a1);
    float inv = 1.0f / (1.0f + wsum_of(dcw));
    float2 xv = __half22float2(*reinterpret_cast<const __half2*>(&srcu[wid * 64 + lane]));
    float2 bb = (lane < 32) ? reinterpret_cast<const float2*>(bmu)[lane]
                            : reinterpret_cast<const float2*>(bls)[lane - 32];
    float2 o = make_float2(a0 + xv.x * inv + bb.x, a1 + xv.y * inv + bb.y);
    // cols 0..63 (lanes 0..31) -> mu ; cols 64..127 (lanes 32..63) -> logstd
    if (lane < 32)
        reinterpret_cast<float2*>(out)[wid * 32 + lane] = o;
    else
        reinterpret_cast<float2*>(out + (size_t)n * 64)[wid * 32 + (lane - 32)] = o;
}

extern "C" void kernel_launch(void* const* d_in, const int* in_sizes, int n_in,
                              void* d_out, int out_size, void* d_ws, size_t ws_size,
                              hipStream_t stream) {
    const float* x   = (const float*)d_in[0];
    const int*   ei  = (const int*)d_in[1];
    const float* ew  = (const float*)d_in[2];
    const float* W1  = (const float*)d_in[3];
    const float* b1  = (const float*)d_in[4];
    const float* Wmu = (const float*)d_in[5];
    const float* bmu = (const float*)d_in[6];
    const float* Wls = (const float*)d_in[7];
    const float* bls = (const float*)d_in[8];
    float* out = (float*)d_out;

    // workspace layout (u32 units; all bases 16B-aligned)
    u64*   dc    = (u64*)d_ws;                       // 50000 u64 (100000 u32)
    u32x2* sed8  = (u32x2*)((u32*)d_ws + 100000);    // N*CAP u32x2 (25.6 MB)
    f16*   Wc1   = (f16*)((u32*)d_ws + 6500000);     // 16384 f16
    f16*   Wc2   = (f16*)((u32*)d_ws + 6508192);     // 16384 f16
    f16*   Abuf  = (f16*)((u32*)d_ws + 6516384);     // [N][128] f16 (xw -> hw)
    f16*   Hbuf  = (f16*)((u32*)d_ws + 9716384);     // [N][128] f16 (h)

    const int N = N_NODES, E = N_EDGES;
    const int NB = (N + 255) / 256;   // 196
    const int WB = (N + 3) / 4;       // wave-per-node kernels: 4 waves/block

    prep<<<NB, 256, 0, stream>>>(W1, Wmu, Wls, Wc1, Wc2, dc, N);

    // FUSED: layer-1 GEMM (first) + bucket-CSR histogram/fill
    gemm1_hist<<<GEMM1_BLOCKS + HIST_BLOCKS, 256, 0, stream>>>(
        x, Wc1, Abuf, ei, ew, dc, sed8, N, E);

    rewrite<<<WB, 256, 0, stream>>>(dc, sed8, N);

    gather_relu<<<WB, 256, 0, stream>>>(sed8, dc, Abuf, b1, Hbuf, N);

    // layer 2 (mu‖logstd in one GEMM)
    gemm_l2<<<(N + 63) / 64, 256, 0, stream>>>(Hbuf, Wc2, Abuf, N);
    gather_out<<<WB, 256, 0, stream>>>(sed8, dc, Abuf, bmu, bls, out, N);
}

// Round 19
// 119.559 us; speedup vs baseline: 1.4495x; 1.0404x over previous
//
#include <hip/hip_runtime.h>
#include <hip/hip_fp16.h>

#define N_NODES 50000
#define N_EDGES 600000
#define CAP 64   // bucket capacity per node (max degree ~40 for Poisson(12))
#define GEMM1_BLOCKS ((N_NODES + 63) / 64)        // 782 (first in fused grid)
#define HIST_BLOCKS ((N_EDGES / 4 + 255) / 256)   // 586

typedef _Float16 f16;
typedef f16 f16x8 __attribute__((ext_vector_type(8)));
typedef float f32x4 __attribute__((ext_vector_type(4)));
typedef unsigned int u32;
typedef unsigned long long u64;
typedef u32 u32x2 __attribute__((ext_vector_type(2)));
typedef u32 u32x4 __attribute__((ext_vector_type(4)));

#define WSCALE 33554432.0f   // 2^25

__device__ __forceinline__ float wsum_of(u64 dcv) {
    return (float)(u32)(dcv & 0xFFFFFFFFu) * (1.0f / WSCALE);
}

// ---------------- prep: dc init + f16 weights (one launch) ----------------

__global__ __launch_bounds__(256) void prep(const float* __restrict__ W1,
                                            const float* __restrict__ Wmu,
                                            const float* __restrict__ Wls,
                                            f16* __restrict__ Wc1,
                                            f16* __restrict__ Wc2,
                                            u64* __restrict__ dc, int n) {
    int i = blockIdx.x * 256 + threadIdx.x;
    if (i < 16384) {
        Wc1[i] = (f16)W1[i];
        Wc2[i] = (f16)((i < 8192) ? Wmu[i] : Wls[i - 8192]);
    }
    if (i < n) dc[i] = 0ULL;
}

// ---------------- GEMM device body: sA-only LDS (16KB), W direct from L2 ------

template<bool A_F16>
__device__ __forceinline__ void gemm_body(const void* __restrict__ Aptr,
                                          const f16* __restrict__ Wc,
                                          f16* __restrict__ Cout, int M, int bid,
                                          f16* sA) {
    const int tid = threadIdx.x;
    const int row0 = bid * 64;

    if (A_F16) {
        const u32x4* src = (const u32x4*)Aptr;   // row-major [M][128] f16
        u32x4* dst = (u32x4*)sA;
        #pragma unroll
        for (int i = 0; i < 4; ++i) {
            int c = tid + i * 256;
            int r = c >> 4, ch = c & 15;
            int gr = row0 + r;
            u32x4 v = {};
            if (gr < M) v = src[gr * 16 + ch];
            dst[r * 16 + (ch ^ (r & 15))] = v;
        }
    } else {
        const float4* src = (const float4*)Aptr;   // fp32 x, row-major [M][128]
        u32x4* dst = (u32x4*)sA;
        #pragma unroll
        for (int i = 0; i < 4; ++i) {
            int c = tid + i * 256;
            int r = c >> 4, ch = c & 15;
            int gr = row0 + r;
            f16x8 h = {};
            if (gr < M) {
                float4 a = src[gr * 32 + ch * 2];
                float4 b = src[gr * 32 + ch * 2 + 1];
                h[0] = (f16)a.x; h[1] = (f16)a.y; h[2] = (f16)a.z; h[3] = (f16)a.w;
                h[4] = (f16)b.x; h[5] = (f16)b.y; h[6] = (f16)b.z; h[7] = (f16)b.w;
            }
            dst[r * 16 + (ch ^ (r & 15))] = *(const u32x4*)&h;
        }
    }
    __syncthreads();

    const int wave = tid >> 6, lane = tid & 63;
    const int m = lane & 15, kq = lane >> 4;
    const int wcol0 = wave * 32;

    f32x4 acc[4][2] = {};
    const f16x8* sa = (const f16x8*)sA;
    const f16x8* W8 = (const f16x8*)Wc;    // [128 rows][16 chunks]

    #pragma unroll
    for (int ks = 0; ks < 4; ++ks) {
        int cidx = ks * 4 + kq;
        f16x8 bfrag[2];
        #pragma unroll
        for (int cf = 0; cf < 2; ++cf)
            bfrag[cf] = W8[(wcol0 + cf * 16 + m) * 16 + cidx];   // direct from L2
        #pragma unroll
        for (int rf = 0; rf < 4; ++rf) {
            int ar = rf * 16 + m;
            f16x8 afrag = sa[ar * 16 + (cidx ^ m)];
            #pragma unroll
            for (int cf = 0; cf < 2; ++cf)
                acc[rf][cf] = __builtin_amdgcn_mfma_f32_16x16x32_f16(
                    afrag, bfrag[cf], acc[rf][cf], 0, 0, 0);
        }
    }

    __syncthreads();                 // done reading sA; reuse as output tile
    #pragma unroll
    for (int rf = 0; rf < 4; ++rf)
        #pragma unroll
        for (int cf = 0; cf < 2; ++cf)
            #pragma unroll
            for (int r = 0; r < 4; ++r)
                sA[(rf * 16 + kq * 4 + r) * 128 + wcol0 + cf * 16 + m] =
                    (f16)acc[rf][cf][r];
    __syncthreads();
    {
        const u32x4* src = (const u32x4*)sA;
        u32x4* dst = (u32x4*)Cout;
        #pragma unroll
        for (int i = 0; i < 4; ++i) {
            int c = tid + i * 256;
            int r = c >> 4, ch = c & 15;
            int gr = row0 + r;
            if (gr < M) dst[gr * 16 + ch] = src[c];
        }
    }
}

// ---------------- FUSED: GEMM1 blocks first + hist_fill4 blocks ----------------
// hist stores 8B {f32 w, u32 r} records (R15-measured-fastest form).

__global__ __launch_bounds__(256) void gemm1_hist(const float* __restrict__ x,
                                                  const f16* __restrict__ Wc1,
                                                  f16* __restrict__ Cout,
                                                  const int* __restrict__ ei,
                                                  const float* __restrict__ ew,
                                                  u64* __restrict__ dc,
                                                  u32x2* __restrict__ sed8,
                                                  int M, int E) {
    __shared__ f16 sA[64 * 128];
    if (blockIdx.x < GEMM1_BLOCKS) {
        gemm_body<false>(x, Wc1, Cout, M, blockIdx.x, sA);
        return;
    }
    // ---- hist_fill4 part: 4 consecutive edges per thread ----
    int t = (blockIdx.x - GEMM1_BLOCKS) * 256 + threadIdx.x;
    int e = 4 * t;
    if (e >= E) return;                       // E % 4 == 0 -> all 4 valid
    int4  r = *reinterpret_cast<const int4*>(ei + e);
    int4  c = *reinterpret_cast<const int4*>(ei + E + e);
    float4 w = *reinterpret_cast<const float4*>(ew + e);

    u64 old0 = 0, old1 = 0, old2 = 0, old3 = 0;
    bool k0 = r.x != c.x, k1 = r.y != c.y, k2 = r.z != c.z, k3 = r.w != c.w;
    if (k0) old0 = atomicAdd(&dc[c.x], (1ULL << 32) | (u64)(u32)__float2uint_rn(w.x * WSCALE));
    if (k1) old1 = atomicAdd(&dc[c.y], (1ULL << 32) | (u64)(u32)__float2uint_rn(w.y * WSCALE));
    if (k2) old2 = atomicAdd(&dc[c.z], (1ULL << 32) | (u64)(u32)__float2uint_rn(w.z * WSCALE));
    if (k3) old3 = atomicAdd(&dc[c.w], (1ULL << 32) | (u64)(u32)__float2uint_rn(w.w * WSCALE));

    u32x2 rec;
    if (k0) { rec.x = __float_as_uint(w.x); rec.y = (u32)r.x; sed8[(size_t)c.x * CAP + (u32)(old0 >> 32)] = rec; }
    if (k1) { rec.x = __float_as_uint(w.y); rec.y = (u32)r.y; sed8[(size_t)c.y * CAP + (u32)(old1 >> 32)] = rec; }
    if (k2) { rec.x = __float_as_uint(w.z); rec.y = (u32)r.z; sed8[(size_t)c.z * CAP + (u32)(old2 >> 32)] = rec; }
    if (k3) { rec.x = __float_as_uint(w.w); rec.y = (u32)r.w; sed8[(size_t)c.w * CAP + (u32)(old3 >> 32)] = rec; }
}

// plain GEMM wrapper for layer 2
__global__ __launch_bounds__(256) void gemm_l2(const f16* __restrict__ Aptr,
                                               const f16* __restrict__ Wc,
                                               f16* __restrict__ Cout, int M) {
    __shared__ f16 sA[64 * 128];
    gemm_body<true>(Aptr, Wc, Cout, M, blockIdx.x, sA);
}

// ---------------- bucket gather + fused epilogues (row-major [N][128] f16 src) ----

__device__ __forceinline__ void bucket_gather(const u32x2* __restrict__ eb,
                                              const u32* __restrict__ srcu,
                                              int pad, int lane,
                                              float& a0, float& a1) {
    for (int p = 0; p < pad; p += 16) {
        #pragma unroll
        for (int j = 0; j < 16; ++j) {
            u32x2 d = eb[p + j];
            float nm = __uint_as_float(d.x);
            __half2 hv = *reinterpret_cast<const __half2*>(&srcu[d.y + lane]);
            float2 v = __half22float2(hv);
            a0 += nm * v.x;
            a1 += nm * v.y;
        }
    }
}

// gather_relu WITH fused rewrite prologue: the wave converts its OWN bucket
// {f32 w, u32 r} -> {f32 norm, r*64} (lane-parallel, pad-zeroed) then gathers;
// re-reads are L1-hot. gather_out (later dispatch) sees rewritten buckets.
__global__ __launch_bounds__(256) void gather_relu(u32x2* __restrict__ sed8,
                                                   const u64* __restrict__ dc,
                                                   const f16* __restrict__ xw,  // [n][128]
                                                   const float* __restrict__ b,
                                                   f16* __restrict__ h, int n) { // [n][128]
    int wid = blockIdx.x * 4 + (threadIdx.x >> 6);
    int lane = threadIdx.x & 63;
    if (wid >= n) return;
    u32x2* eb = sed8 + (size_t)wid * CAP;
    u64 dcw = dc[wid];
    int cnt = (int)(dcw >> 32);
    int pad = (cnt + 15) & ~15;

    // ---- rewrite prologue (lane-parallel, wave-local) ----
    if (lane < pad) {
        u32x2 rec;
        if (lane < cnt) {
            u32x2 d = eb[lane];
            int r = (int)d.y;
            float w = __uint_as_float(d.x);
            float dis_own = rsqrtf(1.0f + wsum_of(dcw));
            float dis_r   = rsqrtf(1.0f + wsum_of(dc[r]));
            rec.x = __float_as_uint(dis_own * w * dis_r);
            rec.y = (u32)r * 64u;
        } else {
            rec.x = 0u; rec.y = (u32)(wid * 64);   // zero-weight pad
        }
        eb[lane] = rec;
    }

    const u32* srcu = (const u32*)xw;
    float a0 = 0.f, a1 = 0.f;
    bucket_gather(eb, srcu, pad, lane, a0, a1);
    float inv = 1.0f / (1.0f + wsum_of(dcw));   // 1/deg
    float2 xv = __half22float2(*reinterpret_cast<const __half2*>(&srcu[wid * 64 + lane]));
    float2 bb = reinterpret_cast<const float2*>(b)[lane];
    float o0 = fmaxf(a0 + xv.x * inv + bb.x, 0.f);
    float o1 = fmaxf(a1 + xv.y * inv + bb.y, 0.f);
    reinterpret_cast<__half2*>(h)[wid * 64 + lane] = __floats2half2_rn(o0, o1);
}

__global__ __launch_bounds__(256) void gather_out(const u32x2* __restrict__ sed8,
                                                  const u64* __restrict__ dc,
                                                  const f16* __restrict__ hw,  // [n][128]
                                                  const float* __restrict__ bmu,
                                                  const float* __restrict__ bls,
                                                  float* __restrict__ out, int n) {
    int wid = blockIdx.x * 4 + (threadIdx.x >> 6);
    int lane = threadIdx.x & 63;
    if (wid >= n) return;
    const u32* srcu = (const u32*)hw;
    u64 dcw = dc[wid];
    int cnt = (int)(dcw >> 32);
    int pad = (cnt + 15) & ~15;
    float a0 = 0.f, a1 = 0.f;
    bucket_gather(sed8 + (size_t)wid * CAP, srcu, pad, lane, a0, a1);
    float inv = 1.0f / (1.0f + wsum_of(dcw));
    float2 xv = __half22float2(*reinterpret_cast<const __half2*>(&srcu[wid * 64 + lane]));
    float2 bb = (lane < 32) ? reinterpret_cast<const float2*>(bmu)[lane]
                            : reinterpret_cast<const float2*>(bls)[lane - 32];
    float2 o = make_float2(a0 + xv.x * inv + bb.x, a1 + xv.y * inv + bb.y);
    // cols 0..63 (lanes 0..31) -> mu ; cols 64..127 (lanes 32..63) -> logstd
    if (lane < 32)
        reinterpret_cast<float2*>(out)[wid * 32 + lane] = o;
    else
        reinterpret_cast<float2*>(out + (size_t)n * 64)[wid * 32 + (lane - 32)] = o;
}

extern "C" void kernel_launch(void* const* d_in, const int* in_sizes, int n_in,
                              void* d_out, int out_size, void* d_ws, size_t ws_size,
                              hipStream_t stream) {
    const float* x   = (const float*)d_in[0];
    const int*   ei  = (const int*)d_in[1];
    const float* ew  = (const float*)d_in[2];
    const float* W1  = (const float*)d_in[3];
    const float* b1  = (const float*)d_in[4];
    const float* Wmu = (const float*)d_in[5];
    const float* bmu = (const float*)d_in[6];
    const float* Wls = (const float*)d_in[7];
    const float* bls = (const float*)d_in[8];
    float* out = (float*)d_out;

    // workspace layout (u32 units; all bases 16B-aligned)
    u64*   dc    = (u64*)d_ws;                       // 50000 u64 (100000 u32)
    u32x2* sed8  = (u32x2*)((u32*)d_ws + 100000);    // N*CAP u32x2 (25.6 MB)
    f16*   Wc1   = (f16*)((u32*)d_ws + 6500000);     // 16384 f16
    f16*   Wc2   = (f16*)((u32*)d_ws + 6508192);     // 16384 f16
    f16*   Abuf  = (f16*)((u32*)d_ws + 6516384);     // [N][128] f16 (xw -> hw)
    f16*   Hbuf  = (f16*)((u32*)d_ws + 9716384);     // [N][128] f16 (h)

    const int N = N_NODES, E = N_EDGES;
    const int NB = (N + 255) / 256;   // 196
    const int WB = (N + 3) / 4;       // wave-per-node kernels: 4 waves/block

    prep<<<NB, 256, 0, stream>>>(W1, Wmu, Wls, Wc1, Wc2, dc, N);

    // FUSED: layer-1 GEMM (first) + bucket-CSR histogram/fill
    gemm1_hist<<<GEMM1_BLOCKS + HIST_BLOCKS, 256, 0, stream>>>(
        x, Wc1, Abuf, ei, ew, dc, sed8, N, E);

    // gather_relu fuses the bucket rewrite as a wave-local prologue
    gather_relu<<<WB, 256, 0, stream>>>(sed8, dc, Abuf, b1, Hbuf, N);

    // layer 2 (mu‖logstd in one GEMM)
    gemm_l2<<<(N + 63) / 64, 256, 0, stream>>>(Hbuf, Wc2, Abuf, N);
    gather_out<<<WB, 256, 0, stream>>>(sed8, dc, Abuf, bmu, bls, out, N);
}